// Round 6
// baseline (76.154 us; speedup 1.0000x reference)
//
#include <hip/hip_runtime.h>
#include <cfloat>

// Shapes (fixed by reference)
#define Bb 4
#define Tt 12
#define Nn 307
#define Cc 64
#define TH 6000
#define Wn 200        // number of windows: starts = 0,30,...,5970
#define ROW (Nn*Cc)   // 19648 floats per time-row
#define QTR (ROW/4)   // 4912
#define NT (Tt*Nn)    // 3684
#define KTOP 10
#define NUMEL 943104.0f  // B*64*N*T
#define NPART 48      // partials per window: t(12) x quarter(4)

// workspace layout (float offsets)
#define WS_MT   0                      // 4096  : Mt[c'*64+c]
#define WS_BC   4096                   // 64    : Bc[c] = 4*sum_o Wk[o,c]*bq[o]
#define WS_QWL  4160                   // 235776: QWl[t][n][c]
#define WS_PART (WS_QWL + Tt*ROW)      // 9600  : partial sims per (w, t*4+q)

typedef float f4 __attribute__((ext_vector_type(4)));

// ---------- Kernel A: precompute Mt (= Wk^T Wq, transposed store) and Bc ----------
__global__ void prep_kernel(const float* __restrict__ Wq, const float* __restrict__ bq,
                            const float* __restrict__ Wk, float* __restrict__ ws) {
    __shared__ float wq[4096], wk[4096];
    for (int i = threadIdx.x; i < 4096; i += 256) { wq[i] = Wq[i]; wk[i] = Wk[i]; }
    __syncthreads();
    float* Mt = ws + WS_MT;
    for (int e = threadIdx.x; e < 4096; e += 256) {
        int cp = e >> 6, c = e & 63;
        float s = 0.f;
        #pragma unroll 8
        for (int o = 0; o < 64; ++o) s += wk[o*64 + c] * wq[o*64 + cp];
        Mt[e] = s;  // Mt[cp*64 + c]
    }
    if (threadIdx.x < 64) {
        int c = threadIdx.x;
        float s = 0.f;
        #pragma unroll 8
        for (int o = 0; o < 64; ++o) s += wk[o*64 + c] * bq[o];
        ws[WS_BC + c] = 4.0f * s;
    }
}

// ---------- Kernel B: QWl[t][n][c] = sum_c' Mt[c'][c]*Xs[t,n,c'] + Bc[c] ----------
__global__ void qw_kernel(const float* __restrict__ x, float* __restrict__ ws) {
    int blk = blockIdx.x;            // t*N + n
    int t = blk / Nn, n = blk % Nn;
    int c = threadIdx.x;             // 64 threads
    size_t base = ((size_t)t * Nn + n) * 64 + c;
    const size_t bs = (size_t)Tt * Nn * 64;
    float xs = x[base] + x[base + bs] + x[base + 2*bs] + x[base + 3*bs];
    __shared__ float xsl[64];
    xsl[c] = xs;
    __syncthreads();
    const float* Mt = ws + WS_MT;
    float q = ws[WS_BC + c];
    #pragma unroll 8
    for (int cp = 0; cp < 64; ++cp) q += Mt[cp*64 + c] * xsl[cp];
    ws[WS_QWL + (size_t)t * ROW + n*64 + c] = q;
}

// ---------- Kernel C: partial sims, 4 windows x quarter-row per block ----------
// One QWl a-load feeds 4 history dots (a-traffic 94->47MB); history loads are
// non-temporal (zero reuse) so QWl stays L2-resident instead of being thrashed
// by the 188.6 MB one-shot stream.
__global__ __launch_bounds__(256) void sims_kernel(const float* __restrict__ hist,
                                                   const float* __restrict__ ws_ro,
                                                   float* __restrict__ part) {
    int b   = blockIdx.x;            // 0..2399
    int wq4 = b / 48;                // 0..49 (window quad)
    int rem = b % 48;                // t*4 + q
    int t = rem >> 2, q = rem & 3;
    int w0 = 4*wq4;
    const f4* a  = (const f4*)(ws_ro + WS_QWL + (size_t)t * ROW + q*QTR);
    const f4* b0 = (const f4*)(hist + (size_t)(30*(w0+0) + t) * ROW + q*QTR);
    const f4* b1 = (const f4*)(hist + (size_t)(30*(w0+1) + t) * ROW + q*QTR);
    const f4* b2 = (const f4*)(hist + (size_t)(30*(w0+2) + t) * ROW + q*QTR);
    const f4* b3 = (const f4*)(hist + (size_t)(30*(w0+3) + t) * ROW + q*QTR);
    float s0 = 0.f, s1 = 0.f, s2 = 0.f, s3 = 0.f;
    for (int i = threadIdx.x; i < QTR/4; i += 256) {
        f4 av = a[i];
        f4 v0 = __builtin_nontemporal_load(&b0[i]);
        f4 v1 = __builtin_nontemporal_load(&b1[i]);
        f4 v2 = __builtin_nontemporal_load(&b2[i]);
        f4 v3 = __builtin_nontemporal_load(&b3[i]);
        s0 += av[0]*v0[0] + av[1]*v0[1] + av[2]*v0[2] + av[3]*v0[3];
        s1 += av[0]*v1[0] + av[1]*v1[1] + av[2]*v1[2] + av[3]*v1[3];
        s2 += av[0]*v2[0] + av[1]*v2[1] + av[2]*v2[2] + av[3]*v2[3];
        s3 += av[0]*v3[0] + av[1]*v3[1] + av[2]*v3[2] + av[3]*v3[3];
    }
    #pragma unroll
    for (int off = 32; off > 0; off >>= 1) {
        s0 += __shfl_down(s0, off);
        s1 += __shfl_down(s1, off);
        s2 += __shfl_down(s2, off);
        s3 += __shfl_down(s3, off);
    }
    __shared__ float red[4][4];      // [wave][win]
    int wave = threadIdx.x >> 6;
    if ((threadIdx.x & 63) == 0) {
        red[wave][0] = s0; red[wave][1] = s1; red[wave][2] = s2; red[wave][3] = s3;
    }
    __syncthreads();
    if (threadIdx.x < 4) {           // thread k finalizes window w0+k
        float v = red[0][threadIdx.x] + red[1][threadIdx.x]
                + red[2][threadIdx.x] + red[3][threadIdx.x];
        part[(w0 + threadIdx.x)*NPART + rem] = v;
    }
}

// ---------- Kernel D: fused top-10 + softmax + aggregate + Wv/bv + broadcast ----------
// Every block redundantly recomputes top-k from part[] (identical fixed-order
// arithmetic -> identical result in every block; deterministic).
__global__ void agg_kernel(const float* __restrict__ hist, const float* __restrict__ Wv,
                           const float* __restrict__ bvv, const float* __restrict__ ws,
                           float* __restrict__ out) {
    int blk = blockIdx.x;            // t*N + n
    int t = blk / Nn, n = blk % Nn;
    int lane = threadIdx.x;          // 64 threads, one wave

    // --- top-k selection (JAX tie-break: lowest index) ---
    const float* part = ws + WS_PART;
    float v[4]; int ji[4];
    #pragma unroll
    for (int r = 0; r < 4; ++r) {
        int j = lane + 64*r;  // sims index 0..198; value from window j+1 (sims_all[1:])
        ji[r] = (j < Wn - 1) ? j : (1 << 29);
        if (j < Wn - 1) {
            float s = 0.f;
            #pragma unroll
            for (int i = 0; i < NPART; ++i) s += part[(j + 1)*NPART + i];
            v[r] = s / NUMEL;
        } else v[r] = -FLT_MAX;
    }
    __shared__ float corr_s[KTOP];
    __shared__ float topv[KTOP];
    __shared__ int   topi[KTOP];
    for (int k = 0; k < KTOP; ++k) {
        float bv = -FLT_MAX; int bi = 1 << 29;
        #pragma unroll
        for (int r = 0; r < 4; ++r)
            if (v[r] > bv || (v[r] == bv && ji[r] < bi)) { bv = v[r]; bi = ji[r]; }
        #pragma unroll
        for (int off = 32; off > 0; off >>= 1) {
            float ov = __shfl_xor(bv, off);
            int   oi = __shfl_xor(bi, off);
            if (ov > bv || (ov == bv && oi < bi)) { bv = ov; bi = oi; }
        }
        if (lane == 0) { topv[k] = bv; topi[k] = bi; }
        #pragma unroll
        for (int r = 0; r < 4; ++r) if (ji[r] == bi) v[r] = -FLT_MAX;
    }
    __syncthreads();
    if (lane == 0) {
        float m = topv[0];
        float sum = 0.f, e[KTOP];
        for (int k = 0; k < KTOP; ++k) { e[k] = __expf(topv[k] - m); sum += e[k]; }
        float inv = 1.0f / sum;
        for (int k = 0; k < KTOP; ++k) corr_s[k] = e[k] * inv;
    }
    __syncthreads();

    // --- aggregate + Wv + bv + broadcast (c = lane doubles as output channel o) ---
    int c = lane;
    float a = 0.f;
    #pragma unroll
    for (int k = 0; k < KTOP; ++k) {
        int w = topi[k];             // reference gathers windows[index] (un-shifted!)
        a += corr_s[k] * hist[(size_t)(30*w + t) * ROW + n*64 + c];
    }
    __shared__ float aw[64];
    aw[c] = a;
    __syncthreads();
    float acc = bvv[c];
    #pragma unroll 8
    for (int cc = 0; cc < 64; ++cc) acc += Wv[c*64 + cc] * aw[cc];
    #pragma unroll
    for (int b = 0; b < Bb; ++b)
        out[(((size_t)b*Tt + t)*Nn + n)*64 + c] = acc;
}

extern "C" void kernel_launch(void* const* d_in, const int* in_sizes, int n_in,
                              void* d_out, int out_size, void* d_ws, size_t ws_size,
                              hipStream_t stream) {
    const float* x    = (const float*)d_in[0];
    const float* hist = (const float*)d_in[1];
    const float* Wq   = (const float*)d_in[2];
    const float* bq   = (const float*)d_in[3];
    const float* Wk   = (const float*)d_in[4];
    // d_in[5] = bk: unused — uniform shift to all sims; top-k ordering and
    // softmax are shift-invariant, so the output is unaffected.
    const float* Wv   = (const float*)d_in[6];
    const float* bv   = (const float*)d_in[7];
    float* ws  = (float*)d_ws;
    float* out = (float*)d_out;

    prep_kernel<<<1, 256, 0, stream>>>(Wq, bq, Wk, ws);
    qw_kernel<<<NT, 64, 0, stream>>>(x, ws);
    sims_kernel<<<50*48, 256, 0, stream>>>(hist, ws, ws + WS_PART);
    agg_kernel<<<NT, 64, 0, stream>>>(hist, Wv, bv, ws, out);
}

// Round 7
// 74.978 us; speedup vs baseline: 1.0157x; 1.0157x over previous
//
#include <hip/hip_runtime.h>
#include <cfloat>

// Shapes (fixed by reference)
#define Bb 4
#define Tt 12
#define Nn 307
#define Cc 64
#define TH 6000
#define Wn 200        // number of windows: starts = 0,30,...,5970
#define ROW (Nn*Cc)   // 19648 floats per time-row
#define QTR (ROW/4)   // 4912
#define NT (Tt*Nn)    // 3684
#define KTOP 10
#define NUMEL 943104.0f  // B*64*N*T
#define NPART 48      // partials per window: t(12) x quarter(4)

// workspace layout (float offsets)
#define WS_MT   0                      // 4096  : Mt[c'*64+c]
#define WS_BC   4096                   // 64    : Bc[c] = 4*sum_o Wk[o,c]*bq[o]
#define WS_QWL  4160                   // 235776: QWl[t][n][c]
#define WS_PART (WS_QWL + Tt*ROW)      // 9600  : partial sims per (w, t*4+q)

typedef float f4 __attribute__((ext_vector_type(4)));

// ---------- Kernel A: precompute Mt (= Wk^T Wq, transposed store) and Bc ----------
__global__ void prep_kernel(const float* __restrict__ Wq, const float* __restrict__ bq,
                            const float* __restrict__ Wk, float* __restrict__ ws) {
    __shared__ float wq[4096], wk[4096];
    for (int i = threadIdx.x; i < 4096; i += 256) { wq[i] = Wq[i]; wk[i] = Wk[i]; }
    __syncthreads();
    float* Mt = ws + WS_MT;
    for (int e = threadIdx.x; e < 4096; e += 256) {
        int cp = e >> 6, c = e & 63;
        float s = 0.f;
        #pragma unroll 8
        for (int o = 0; o < 64; ++o) s += wk[o*64 + c] * wq[o*64 + cp];
        Mt[e] = s;  // Mt[cp*64 + c]
    }
    if (threadIdx.x < 64) {
        int c = threadIdx.x;
        float s = 0.f;
        #pragma unroll 8
        for (int o = 0; o < 64; ++o) s += wk[o*64 + c] * bq[o];
        ws[WS_BC + c] = 4.0f * s;
    }
}

// ---------- Kernel B: QWl[t][n][c] = sum_c' Mt[c'][c]*Xs[t,n,c'] + Bc[c] ----------
__global__ void qw_kernel(const float* __restrict__ x, float* __restrict__ ws) {
    int blk = blockIdx.x;            // t*N + n
    int t = blk / Nn, n = blk % Nn;
    int c = threadIdx.x;             // 64 threads
    size_t base = ((size_t)t * Nn + n) * 64 + c;
    const size_t bs = (size_t)Tt * Nn * 64;
    float xs = x[base] + x[base + bs] + x[base + 2*bs] + x[base + 3*bs];
    __shared__ float xsl[64];
    xsl[c] = xs;
    __syncthreads();
    const float* Mt = ws + WS_MT;
    float q = ws[WS_BC + c];
    #pragma unroll 8
    for (int cp = 0; cp < 64; ++cp) q += Mt[cp*64 + c] * xsl[cp];
    ws[WS_QWL + (size_t)t * ROW + n*64 + c] = q;
}

// ---------- Kernel C: partial sims, 4 windows x quarter-row per block ----------
// QWl quarter-row staged in LDS once per block -> inner-loop VMEM traffic is
// 100% history stream (4 independent chains); a-reads move to the lgkm pipe.
// No non-temporal hints (R6 showed nt regressed read throughput).
__global__ __launch_bounds__(256) void sims_kernel(const float* __restrict__ hist,
                                                   const float* __restrict__ ws_ro,
                                                   float* __restrict__ part) {
    __shared__ float a_lds[QTR];     // 19648 B -> still 8 blocks/CU (32 waves)
    int b   = blockIdx.x;            // 0..2399
    int wq4 = b / 48;                // 0..49 (window quad)
    int rem = b % 48;                // t*4 + q
    int t = rem >> 2, q = rem & 3;
    int w0 = 4*wq4;
    const f4* asrc = (const f4*)(ws_ro + WS_QWL + (size_t)t * ROW + q*QTR);
    for (int i = threadIdx.x; i < QTR/4; i += 256)
        ((f4*)a_lds)[i] = asrc[i];
    __syncthreads();
    const f4* b0 = (const f4*)(hist + (size_t)(30*(w0+0) + t) * ROW + q*QTR);
    const f4* b1 = (const f4*)(hist + (size_t)(30*(w0+1) + t) * ROW + q*QTR);
    const f4* b2 = (const f4*)(hist + (size_t)(30*(w0+2) + t) * ROW + q*QTR);
    const f4* b3 = (const f4*)(hist + (size_t)(30*(w0+3) + t) * ROW + q*QTR);
    float s0 = 0.f, s1 = 0.f, s2 = 0.f, s3 = 0.f;
    for (int i = threadIdx.x; i < QTR/4; i += 256) {
        f4 av = ((const f4*)a_lds)[i];
        f4 v0 = b0[i], v1 = b1[i], v2 = b2[i], v3 = b3[i];
        s0 += av[0]*v0[0] + av[1]*v0[1] + av[2]*v0[2] + av[3]*v0[3];
        s1 += av[0]*v1[0] + av[1]*v1[1] + av[2]*v1[2] + av[3]*v1[3];
        s2 += av[0]*v2[0] + av[1]*v2[1] + av[2]*v2[2] + av[3]*v2[3];
        s3 += av[0]*v3[0] + av[1]*v3[1] + av[2]*v3[2] + av[3]*v3[3];
    }
    #pragma unroll
    for (int off = 32; off > 0; off >>= 1) {
        s0 += __shfl_down(s0, off);
        s1 += __shfl_down(s1, off);
        s2 += __shfl_down(s2, off);
        s3 += __shfl_down(s3, off);
    }
    __shared__ float red[4][4];      // [wave][win]
    int wave = threadIdx.x >> 6;
    if ((threadIdx.x & 63) == 0) {
        red[wave][0] = s0; red[wave][1] = s1; red[wave][2] = s2; red[wave][3] = s3;
    }
    __syncthreads();
    if (threadIdx.x < 4) {           // thread k finalizes window w0+k
        float v = red[0][threadIdx.x] + red[1][threadIdx.x]
                + red[2][threadIdx.x] + red[3][threadIdx.x];
        part[(w0 + threadIdx.x)*NPART + rem] = v;
    }
}

// ---------- Kernel D: fused top-10 + softmax + aggregate + Wv/bv + broadcast ----------
// Every block redundantly recomputes top-k from part[] (identical fixed-order
// arithmetic -> identical result in every block; deterministic).
__global__ void agg_kernel(const float* __restrict__ hist, const float* __restrict__ Wv,
                           const float* __restrict__ bvv, const float* __restrict__ ws,
                           float* __restrict__ out) {
    int blk = blockIdx.x;            // t*N + n
    int t = blk / Nn, n = blk % Nn;
    int lane = threadIdx.x;          // 64 threads, one wave

    // --- top-k selection (JAX tie-break: lowest index) ---
    const float* part = ws + WS_PART;
    float v[4]; int ji[4];
    #pragma unroll
    for (int r = 0; r < 4; ++r) {
        int j = lane + 64*r;  // sims index 0..198; value from window j+1 (sims_all[1:])
        ji[r] = (j < Wn - 1) ? j : (1 << 29);
        if (j < Wn - 1) {
            float s = 0.f;
            #pragma unroll
            for (int i = 0; i < NPART; ++i) s += part[(j + 1)*NPART + i];
            v[r] = s / NUMEL;
        } else v[r] = -FLT_MAX;
    }
    __shared__ float corr_s[KTOP];
    __shared__ float topv[KTOP];
    __shared__ int   topi[KTOP];
    for (int k = 0; k < KTOP; ++k) {
        float bv = -FLT_MAX; int bi = 1 << 29;
        #pragma unroll
        for (int r = 0; r < 4; ++r)
            if (v[r] > bv || (v[r] == bv && ji[r] < bi)) { bv = v[r]; bi = ji[r]; }
        #pragma unroll
        for (int off = 32; off > 0; off >>= 1) {
            float ov = __shfl_xor(bv, off);
            int   oi = __shfl_xor(bi, off);
            if (ov > bv || (ov == bv && oi < bi)) { bv = ov; bi = oi; }
        }
        if (lane == 0) { topv[k] = bv; topi[k] = bi; }
        #pragma unroll
        for (int r = 0; r < 4; ++r) if (ji[r] == bi) v[r] = -FLT_MAX;
    }
    __syncthreads();
    if (lane == 0) {
        float m = topv[0];
        float sum = 0.f, e[KTOP];
        for (int k = 0; k < KTOP; ++k) { e[k] = __expf(topv[k] - m); sum += e[k]; }
        float inv = 1.0f / sum;
        for (int k = 0; k < KTOP; ++k) corr_s[k] = e[k] * inv;
    }
    __syncthreads();

    // --- aggregate + Wv + bv + broadcast (c = lane doubles as output channel o) ---
    int c = lane;
    float a = 0.f;
    #pragma unroll
    for (int k = 0; k < KTOP; ++k) {
        int w = topi[k];             // reference gathers windows[index] (un-shifted!)
        a += corr_s[k] * hist[(size_t)(30*w + t) * ROW + n*64 + c];
    }
    __shared__ float aw[64];
    aw[c] = a;
    __syncthreads();
    float acc = bvv[c];
    #pragma unroll 8
    for (int cc = 0; cc < 64; ++cc) acc += Wv[c*64 + cc] * aw[cc];
    #pragma unroll
    for (int b = 0; b < Bb; ++b)
        out[(((size_t)b*Tt + t)*Nn + n)*64 + c] = acc;
}

extern "C" void kernel_launch(void* const* d_in, const int* in_sizes, int n_in,
                              void* d_out, int out_size, void* d_ws, size_t ws_size,
                              hipStream_t stream) {
    const float* x    = (const float*)d_in[0];
    const float* hist = (const float*)d_in[1];
    const float* Wq   = (const float*)d_in[2];
    const float* bq   = (const float*)d_in[3];
    const float* Wk   = (const float*)d_in[4];
    // d_in[5] = bk: unused — uniform shift to all sims; top-k ordering and
    // softmax are shift-invariant, so the output is unaffected.
    const float* Wv   = (const float*)d_in[6];
    const float* bv   = (const float*)d_in[7];
    float* ws  = (float*)d_ws;
    float* out = (float*)d_out;

    prep_kernel<<<1, 256, 0, stream>>>(Wq, bq, Wk, ws);
    qw_kernel<<<NT, 64, 0, stream>>>(x, ws);
    sims_kernel<<<50*48, 256, 0, stream>>>(hist, ws, ws + WS_PART);
    agg_kernel<<<NT, 64, 0, stream>>>(hist, Wv, bv, ws, out);
}

// Round 8
// 70.639 us; speedup vs baseline: 1.0781x; 1.0614x over previous
//
#include <hip/hip_runtime.h>
#include <cfloat>

// Shapes (fixed by reference)
#define Bb 4
#define Tt 12
#define Nn 307
#define Cc 64
#define TH 6000
#define Wn 200        // number of windows: starts = 0,30,...,5970
#define ROW (Nn*Cc)   // 19648 floats per time-row
#define HALF (ROW/2)  // 9824
#define NT (Tt*Nn)    // 3684
#define KTOP 10
#define NUMEL 943104.0f  // B*64*N*T
#define NPART 24      // partials per window: t(12) x half(2)

// workspace layout (float offsets)
#define WS_MT   0                      // 4096  : Mt[c'*64+c]
#define WS_BC   4096                   // 64    : Bc[c] = 4*sum_o Wk[o,c]*bq[o]
#define WS_QWL  4160                   // 235776: QWl[t][n][c]
#define WS_PART (WS_QWL + Tt*ROW)      // 4800  : partial sims, TRANSPOSED [i][w]

// ---------- Kernel A: precompute Mt (= Wk^T Wq, transposed store) and Bc ----------
__global__ void prep_kernel(const float* __restrict__ Wq, const float* __restrict__ bq,
                            const float* __restrict__ Wk, float* __restrict__ ws) {
    __shared__ float wq[4096], wk[4096];
    for (int i = threadIdx.x; i < 4096; i += 256) { wq[i] = Wq[i]; wk[i] = Wk[i]; }
    __syncthreads();
    float* Mt = ws + WS_MT;
    for (int e = threadIdx.x; e < 4096; e += 256) {
        int cp = e >> 6, c = e & 63;
        float s = 0.f;
        #pragma unroll 8
        for (int o = 0; o < 64; ++o) s += wk[o*64 + c] * wq[o*64 + cp];
        Mt[e] = s;  // Mt[cp*64 + c]
    }
    if (threadIdx.x < 64) {
        int c = threadIdx.x;
        float s = 0.f;
        #pragma unroll 8
        for (int o = 0; o < 64; ++o) s += wk[o*64 + c] * bq[o];
        ws[WS_BC + c] = 4.0f * s;
    }
}

// ---------- Kernel B: QWl[t][n][c] = sum_c' Mt[c'][c]*Xs[t,n,c'] + Bc[c] ----------
__global__ void qw_kernel(const float* __restrict__ x, float* __restrict__ ws) {
    int blk = blockIdx.x;            // t*N + n
    int t = blk / Nn, n = blk % Nn;
    int c = threadIdx.x;             // 64 threads
    size_t base = ((size_t)t * Nn + n) * 64 + c;
    const size_t bs = (size_t)Tt * Nn * 64;
    float xs = x[base] + x[base + bs] + x[base + 2*bs] + x[base + 3*bs];
    __shared__ float xsl[64];
    xsl[c] = xs;
    __syncthreads();
    const float* Mt = ws + WS_MT;
    float q = ws[WS_BC + c];
    #pragma unroll 8
    for (int cp = 0; cp < 64; ++cp) q += Mt[cp*64 + c] * xsl[cp];
    ws[WS_QWL + (size_t)t * ROW + n*64 + c] = q;
}

// ---------- Kernel C: partial sims, 2 windows x half-row per block (R5 structure) ----------
// part stored TRANSPOSED: part[rem*Wn + w] so agg's top-k reads are coalesced.
__global__ __launch_bounds__(256) void sims_kernel(const float* __restrict__ hist,
                                                   const float* __restrict__ ws_ro,
                                                   float* __restrict__ part) {
    int b   = blockIdx.x;            // 0..2399
    int wp  = b / NPART;             // 0..99
    int rem = b % NPART;             // t*2 + h
    int t = rem >> 1, h = rem & 1;
    int w0 = 2*wp, w1 = w0 + 1;
    const float4* a  = (const float4*)(ws_ro + WS_QWL + (size_t)t * ROW + h*HALF);
    const float4* b0 = (const float4*)(hist + (size_t)(30*w0 + t) * ROW + h*HALF);
    const float4* b1 = (const float4*)(hist + (size_t)(30*w1 + t) * ROW + h*HALF);
    float s0 = 0.f, s1 = 0.f;
    #pragma unroll 2
    for (int i = threadIdx.x; i < HALF/4; i += 256) {
        float4 av = a[i], v0 = b0[i], v1 = b1[i];
        s0 += av.x*v0.x + av.y*v0.y + av.z*v0.z + av.w*v0.w;
        s1 += av.x*v1.x + av.y*v1.y + av.z*v1.z + av.w*v1.w;
    }
    #pragma unroll
    for (int off = 32; off > 0; off >>= 1) {
        s0 += __shfl_down(s0, off);
        s1 += __shfl_down(s1, off);
    }
    __shared__ float red0[4], red1[4];
    int wave = threadIdx.x >> 6;
    if ((threadIdx.x & 63) == 0) { red0[wave] = s0; red1[wave] = s1; }
    __syncthreads();
    if (threadIdx.x == 0) {
        part[rem*Wn + w0] = red0[0] + red0[1] + red0[2] + red0[3];
        part[rem*Wn + w1] = red1[0] + red1[1] + red1[2] + red1[3];
    }
}

// ---------- Kernel D: fused top-10 + softmax + aggregate + Wv/bv + broadcast ----------
// Every block redundantly recomputes top-k from part[] (identical fixed-order
// arithmetic -> identical result in every block; deterministic). part is [i][w]
// so lane-consecutive j reads are coalesced 256B wave-loads.
__global__ void agg_kernel(const float* __restrict__ hist, const float* __restrict__ Wv,
                           const float* __restrict__ bvv, const float* __restrict__ ws,
                           float* __restrict__ out) {
    int blk = blockIdx.x;            // t*N + n
    int t = blk / Nn, n = blk % Nn;
    int lane = threadIdx.x;          // 64 threads, one wave

    // --- top-k selection (JAX tie-break: lowest index) ---
    const float* part = ws + WS_PART;
    float v[4]; int ji[4];
    #pragma unroll
    for (int r = 0; r < 4; ++r) {
        int j = lane + 64*r;  // sims index 0..198; value from window j+1 (sims_all[1:])
        ji[r] = (j < Wn - 1) ? j : (1 << 29);
        if (j < Wn - 1) {
            float s = 0.f;
            #pragma unroll
            for (int i = 0; i < NPART; ++i) s += part[i*Wn + (j + 1)];
            v[r] = s / NUMEL;
        } else v[r] = -FLT_MAX;
    }
    __shared__ float corr_s[KTOP];
    __shared__ float topv[KTOP];
    __shared__ int   topi[KTOP];
    for (int k = 0; k < KTOP; ++k) {
        float bv = -FLT_MAX; int bi = 1 << 29;
        #pragma unroll
        for (int r = 0; r < 4; ++r)
            if (v[r] > bv || (v[r] == bv && ji[r] < bi)) { bv = v[r]; bi = ji[r]; }
        #pragma unroll
        for (int off = 32; off > 0; off >>= 1) {
            float ov = __shfl_xor(bv, off);
            int   oi = __shfl_xor(bi, off);
            if (ov > bv || (ov == bv && oi < bi)) { bv = ov; bi = oi; }
        }
        if (lane == 0) { topv[k] = bv; topi[k] = bi; }
        #pragma unroll
        for (int r = 0; r < 4; ++r) if (ji[r] == bi) v[r] = -FLT_MAX;
    }
    __syncthreads();
    if (lane == 0) {
        float m = topv[0];
        float sum = 0.f, e[KTOP];
        for (int k = 0; k < KTOP; ++k) { e[k] = __expf(topv[k] - m); sum += e[k]; }
        float inv = 1.0f / sum;
        for (int k = 0; k < KTOP; ++k) corr_s[k] = e[k] * inv;
    }
    __syncthreads();

    // --- aggregate + Wv + bv + broadcast (c = lane doubles as output channel o) ---
    int c = lane;
    float a = 0.f;
    #pragma unroll
    for (int k = 0; k < KTOP; ++k) {
        int w = topi[k];             // reference gathers windows[index] (un-shifted!)
        a += corr_s[k] * hist[(size_t)(30*w + t) * ROW + n*64 + c];
    }
    __shared__ float aw[64];
    aw[c] = a;
    __syncthreads();
    float acc = bvv[c];
    #pragma unroll 8
    for (int cc = 0; cc < 64; ++cc) acc += Wv[c*64 + cc] * aw[cc];
    #pragma unroll
    for (int b = 0; b < Bb; ++b)
        out[(((size_t)b*Tt + t)*Nn + n)*64 + c] = acc;
}

extern "C" void kernel_launch(void* const* d_in, const int* in_sizes, int n_in,
                              void* d_out, int out_size, void* d_ws, size_t ws_size,
                              hipStream_t stream) {
    const float* x    = (const float*)d_in[0];
    const float* hist = (const float*)d_in[1];
    const float* Wq   = (const float*)d_in[2];
    const float* bq   = (const float*)d_in[3];
    const float* Wk   = (const float*)d_in[4];
    // d_in[5] = bk: unused — uniform shift to all sims; top-k ordering and
    // softmax are shift-invariant, so the output is unaffected.
    const float* Wv   = (const float*)d_in[6];
    const float* bv   = (const float*)d_in[7];
    float* ws  = (float*)d_ws;
    float* out = (float*)d_out;

    prep_kernel<<<1, 256, 0, stream>>>(Wq, bq, Wk, ws);
    qw_kernel<<<NT, 64, 0, stream>>>(x, ws);
    sims_kernel<<<(Wn/2)*NPART, 256, 0, stream>>>(hist, ws, ws + WS_PART);
    agg_kernel<<<NT, 64, 0, stream>>>(hist, Wv, bv, ws, out);
}